// Round 4
// baseline (14608.766 us; speedup 1.0000x reference)
//
#include <hip/hip_runtime.h>
#include <math.h>

typedef _Float16 f16;
typedef f16 f16x2 __attribute__((ext_vector_type(2)));
typedef f16 f16x4 __attribute__((ext_vector_type(4)));
typedef f16 f16x8 __attribute__((ext_vector_type(8)));
typedef float f32x4 __attribute__((ext_vector_type(4)));

#define HDIM 1024
#define SEQ  2048
#define NWRK 16   // worker blocks (one XCD)
#define RPB  64   // rows of W_hh per worker

// ---------------- clear pairs + init election ctrl ----------------
// pairs row 0 cleared to (tag=0,payload=0) doubles as h_0 = 0.
// ctrl[0..7]=cnt per XCD, ctrl[8]=winner (0xFFFFFFFF = none yet).
__global__ void k_clear(unsigned long long* __restrict__ p, int n,
                        unsigned* __restrict__ ctrl) {
  int stride = gridDim.x * blockDim.x;
  for (int i = blockIdx.x * blockDim.x + threadIdx.x; i < n; i += stride)
    p[i] = 0ULL;
  if (blockIdx.x == 0 && threadIdx.x < 16)
    ctrl[threadIdx.x] = (threadIdx.x == 8) ? 0xFFFFFFFFu : 0u;
}

// ---------------- f32 -> f16 convert (vec4, grid-stride) ----------------
__global__ void k_cvt(const float* __restrict__ in, f16* __restrict__ out, int n4) {
  int stride = gridDim.x * blockDim.x;
  for (int i = blockIdx.x * blockDim.x + threadIdx.x; i < n4; i += stride) {
    float4 v = ((const float4*)in)[i];
    f16x4 o = { (f16)v.x, (f16)v.y, (f16)v.z, (f16)v.w };
    ((f16x4*)out)[i] = o;
  }
}

__global__ void k_bias(const float* __restrict__ a, const float* __restrict__ b,
                       float* __restrict__ o) {
  int i = blockIdx.x * blockDim.x + threadIdx.x;
  if (i < HDIM) o[i] = a[i] + b[i];
}

// ---------------- B^T GEMM:  C[M][N] = A[M][K=1024] * B[N][K=1024]^T + bias[N]
__global__ __launch_bounds__(256) void k_gemm(
    const f16* __restrict__ A, const f16* __restrict__ B,
    const float* __restrict__ bias, float* __restrict__ C, int N)
{
  const int K = 1024;
  __shared__ __align__(16) f16 lsA[128 * 32];
  __shared__ __align__(16) f16 lsB[128 * 32];
  const int tid = threadIdx.x;
  const int l   = tid & 63;
  const int wv  = tid >> 6;
  const int mb  = blockIdx.y * 128;
  const int nb  = blockIdx.x * 128;
  const int wm  = (wv >> 1) * 64;
  const int wn  = (wv & 1) * 64;

  f32x4 acc[4][4] = {};

  for (int kt = 0; kt < K; kt += 32) {
    uint4 ra[2], rb[2];
#pragma unroll
    for (int i = 0; i < 2; ++i) {
      int c = tid + i * 256;
      int row = c >> 2, off = (c & 3) * 8;
      ra[i] = *(const uint4*)(A + (size_t)(mb + row) * K + kt + off);
      rb[i] = *(const uint4*)(B + (size_t)(nb + row) * K + kt + off);
    }
    __syncthreads();
#pragma unroll
    for (int i = 0; i < 2; ++i) {
      int c = tid + i * 256;
      *(uint4*)(lsA + c * 8) = ra[i];
      *(uint4*)(lsB + c * 8) = rb[i];
    }
    __syncthreads();

    f16x8 af[4], bf[4];
#pragma unroll
    for (int m = 0; m < 4; ++m)
      af[m] = *(const f16x8*)(lsA + (wm + m * 16 + (l & 15)) * 32 + (l >> 4) * 8);
#pragma unroll
    for (int n = 0; n < 4; ++n)
      bf[n] = *(const f16x8*)(lsB + (wn + n * 16 + (l & 15)) * 32 + (l >> 4) * 8);
#pragma unroll
    for (int m = 0; m < 4; ++m)
#pragma unroll
      for (int n = 0; n < 4; ++n)
        acc[m][n] = __builtin_amdgcn_mfma_f32_16x16x32_f16(af[m], bf[n], acc[m][n], 0, 0, 0);
  }

#pragma unroll
  for (int n = 0; n < 4; ++n) {
    int col = nb + wn + n * 16 + (l & 15);
    float bv = bias[col];
#pragma unroll
    for (int m = 0; m < 4; ++m) {
#pragma unroll
      for (int j = 0; j < 4; ++j) {
        int row = mb + wm + m * 16 + (l >> 4) * 4 + j;
        C[(size_t)row * N + col] = acc[m][n][j] + bv;
      }
    }
  }
}

// ---- L2-scope 8x u64 sweep (bypass L1, hit this XCD's shared L2) ----
__device__ __forceinline__ void ld8_l2(const unsigned long long* p,
                                       unsigned long long u[8]) {
  asm volatile(
      "global_load_dwordx2 %0, %8, off sc0\n\t"
      "global_load_dwordx2 %1, %8, off offset:8 sc0\n\t"
      "global_load_dwordx2 %2, %8, off offset:16 sc0\n\t"
      "global_load_dwordx2 %3, %8, off offset:24 sc0\n\t"
      "global_load_dwordx2 %4, %8, off offset:32 sc0\n\t"
      "global_load_dwordx2 %5, %8, off offset:40 sc0\n\t"
      "global_load_dwordx2 %6, %8, off offset:48 sc0\n\t"
      "global_load_dwordx2 %7, %8, off offset:56 sc0\n\t"
      "s_waitcnt vmcnt(0)"
      : "=&v"(u[0]), "=&v"(u[1]), "=&v"(u[2]), "=&v"(u[3]),
        "=&v"(u[4]), "=&v"(u[5]), "=&v"(u[6]), "=&v"(u[7])
      : "v"(p) : "memory");
}

// ---- MALL-scope sweep (bypass L1+L2) — correctness fallback ----
__device__ __forceinline__ void ld8_mall(const unsigned long long* p,
                                         unsigned long long u[8]) {
  asm volatile(
      "global_load_dwordx2 %0, %8, off sc0 sc1\n\t"
      "global_load_dwordx2 %1, %8, off offset:8 sc0 sc1\n\t"
      "global_load_dwordx2 %2, %8, off offset:16 sc0 sc1\n\t"
      "global_load_dwordx2 %3, %8, off offset:24 sc0 sc1\n\t"
      "global_load_dwordx2 %4, %8, off offset:32 sc0 sc1\n\t"
      "global_load_dwordx2 %5, %8, off offset:40 sc0 sc1\n\t"
      "global_load_dwordx2 %6, %8, off offset:48 sc0 sc1\n\t"
      "global_load_dwordx2 %7, %8, off offset:56 sc0 sc1\n\t"
      "s_waitcnt vmcnt(0)"
      : "=&v"(u[0]), "=&v"(u[1]), "=&v"(u[2]), "=&v"(u[3]),
        "=&v"(u[4]), "=&v"(u[5]), "=&v"(u[6]), "=&v"(u[7])
      : "v"(p) : "memory");
}

// ---- dual store: local L2 (fast visibility) + MALL (global safety) ----
__device__ __forceinline__ void st_dual(unsigned long long* p, unsigned long long v) {
  asm volatile(
      "global_store_dwordx2 %0, %1, off sc0\n\t"
      "global_store_dwordx2 %0, %1, off sc0 sc1"
      :: "v"(p), "v"(v) : "memory");
}

// ---------------- sequential recurrence: 16 workers on ONE XCD ----------------
// Tag-in-data (tag=t | f16x2 payload, single-writer monotone per address):
// any load path (L2 hit, eviction, MALL refill) returns current-or-older, and
// tag==need accepts only current -> staleness delays, never corrupts.
// Election: 256 blocks claim tickets in cnt[XCC_ID]; first XCD with 16 wins.
// Fallback: pollers starving >1024 L2 sweeps latch permanently to MALL sweeps.
__global__ __launch_bounds__(1024) void k_recur(
    const float* __restrict__ W,
    const float* __restrict__ xp,
    unsigned long long* __restrict__ pairs,
    f16* __restrict__ hs,
    unsigned* __restrict__ ctrl)
{
  __shared__ unsigned hl[544];     // 17-stride swizzle
  __shared__ int s_slot;
  __shared__ int s_dead;

  const int tid = threadIdx.x;

  if (tid == 0) {
    s_dead = 0;
    // HW_REG_XCC_ID = id 20, offset 0, size 32 -> simm16 = (31<<11)|20 = 63508
    unsigned xcc = __builtin_amdgcn_s_getreg(63508) & 7u;
    unsigned ticket = __hip_atomic_fetch_add(&ctrl[xcc], 1u,
                                             __ATOMIC_RELAXED, __HIP_MEMORY_SCOPE_AGENT);
    int slot = -1;
    if (ticket < NWRK) {
      if (ticket == NWRK - 1) {
        unsigned expv = 0xFFFFFFFFu;
        __hip_atomic_compare_exchange_strong(&ctrl[8], &expv, xcc,
                                             __ATOMIC_RELAXED, __ATOMIC_RELAXED,
                                             __HIP_MEMORY_SCOPE_AGENT);
      }
      unsigned wv; int g = 0;
      do {
        wv = __hip_atomic_load(&ctrl[8], __ATOMIC_RELAXED, __HIP_MEMORY_SCOPE_AGENT);
      } while (wv == 0xFFFFFFFFu && ++g < (1 << 22));
      if (wv == xcc) slot = (int)ticket;
    }
    s_slot = slot;
  }
  __syncthreads();
  if (s_slot < 0) return;
  const int b = s_slot;

  const int w   = tid >> 6;
  const int l   = tid & 63;
  const int hfl = l >> 5;
  const int ch  = l & 31;
  const int r0  = b * RPB + w * 4 + hfl * 2;
  const int c0  = ch * 32;

  f16x2 wv0[16], wv1[16];
  {
    const float* w0 = W + (size_t)r0 * HDIM + c0;
    const float* w1 = w0 + HDIM;
#pragma unroll
    for (int j = 0; j < 16; ++j) {
      wv0[j] = f16x2{ (f16)w0[2 * j], (f16)w0[2 * j + 1] };
      wv1[j] = f16x2{ (f16)w1[2 * j], (f16)w1[2 * j + 1] };
    }
  }

  const bool poller = (w == 0);
  bool slow = false;               // permanent per-thread latch to MALL polling

  for (unsigned t = 1; t <= SEQ; ++t) {
    float x0 = 0.f, x1 = 0.f;
    if (ch == 0) {
      const float* xr = xp + (size_t)(t - 1) * HDIM + r0;
      x0 = xr[0]; x1 = xr[1];
    }

    if (poller) {
      const unsigned long long* row = pairs + (size_t)(t - 1) * 512 + l * 8;
      const unsigned need = t - 1;
      unsigned long long u[8];
      bool deadf = false;
      int g = 0;
      for (;;) {
        if (!slow) ld8_l2(row, u); else ld8_mall(row, u);
        bool ok = true;
#pragma unroll
        for (int j = 0; j < 8; ++j)
          ok &= ((unsigned)(u[j] >> 32) == need);
        if (ok) break;
        if (++g > (slow ? (1 << 22) : 1024)) {
          if (slow) { deadf = true; break; }
          slow = true; g = 0;
        }
      }
      unsigned long long db = __ballot(deadf);
      if (db && l == 0) s_dead = 1;
      const int base = (l >> 1) * 17 + (l & 1) * 8;
#pragma unroll
      for (int j = 0; j < 8; ++j) hl[base + j] = (unsigned)u[j];
    }
    __syncthreads();
    if (s_dead) return;            // abort cleanly (all threads together)

    float s0 = 0.f, s1 = 0.f;
#pragma unroll
    for (int j = 0; j < 16; ++j) {
      f16x2 hv = __builtin_bit_cast(f16x2, hl[ch * 17 + j]);
      s0 = __builtin_amdgcn_fdot2(wv0[j], hv, s0, false);
      s1 = __builtin_amdgcn_fdot2(wv1[j], hv, s1, false);
    }
#pragma unroll
    for (int m = 16; m >= 1; m >>= 1) {
      s0 += __shfl_xor(s0, m, 64);
      s1 += __shfl_xor(s1, m, 64);
    }

    if (ch == 0) {
      // fast tanh: 1 - 2/(e^{2x}+1); |err| ~1e-6 << f16 storage rounding
      float a0 = x0 + s0, a1 = x1 + s1;
      float e0 = __expf(2.f * a0), e1 = __expf(2.f * a1);
      float h0 = 1.f - 2.f * __builtin_amdgcn_rcpf(e0 + 1.f);
      float h1 = 1.f - 2.f * __builtin_amdgcn_rcpf(e1 + 1.f);
      f16x2 hh = { (f16)h0, (f16)h1 };
      unsigned pay = __builtin_bit_cast(unsigned, hh);
      unsigned long long val = ((unsigned long long)t << 32) | (unsigned long long)pay;
      st_dual(pairs + (size_t)t * 512 + (r0 >> 1), val);
      *(f16x2*)(hs + (size_t)t * HDIM + r0) = hh;   // clean copy for head GEMM
    }
  }
}

// ---------------- launch ----------------
extern "C" void kernel_launch(void* const* d_in, const int* in_sizes, int n_in,
                              void* d_out, int out_size, void* d_ws, size_t ws_size,
                              hipStream_t stream) {
  const float* x    = (const float*)d_in[0];
  const float* W_ih = (const float*)d_in[1];
  const float* W_hh = (const float*)d_in[2];
  const float* b_ih = (const float*)d_in[3];
  const float* b_hh = (const float*)d_in[4];
  const float* W_fc = (const float*)d_in[5];
  const float* b_fc = (const float*)d_in[6];
  float* out = (float*)d_out;

  char* ws = (char*)d_ws;
  unsigned long long* pairs = (unsigned long long*)ws;       // 8,392,704 B
  f16*   hs16  = (f16*)(ws + 8500000);                       // 4,196,352
  float* xp    = (float*)(ws + 12700000);                    // 8,388,608
  f16*   x16   = (f16*)(ws + 21100000);                      // 4,194,304
  f16*   wih16 = (f16*)(ws + 25300000);                      // 2,097,152
  f16*   wfc16 = (f16*)(ws + 27400000);                      // 65,536,000
  float* bsum  = (float*)(ws + 92936000);                    // 4,096
  unsigned* ctrl = (unsigned*)(ws + 92940160);               // 64 B

  k_clear<<<1024, 256, 0, stream>>>(pairs, (SEQ + 1) * 512, ctrl);
  k_cvt<<<1024, 256, 0, stream>>>(x, x16, 2048 * 1024 / 4);
  k_cvt<<<1024, 256, 0, stream>>>(W_ih, wih16, 1024 * 1024 / 4);
  k_cvt<<<2048, 256, 0, stream>>>(W_fc, wfc16, 32000 * 1024 / 4);
  k_bias<<<4, 256, 0, stream>>>(b_ih, b_hh, bsum);

  k_gemm<<<dim3(8, 16), 256, 0, stream>>>(x16, wih16, bsum, xp, 1024);

  k_recur<<<256, 1024, 0, stream>>>(W_hh, xp, pairs, hs16, ctrl);

  k_gemm<<<dim3(250, 16), 256, 0, stream>>>(hs16 + HDIM, wfc16, b_fc, out, 32000);
}

// Round 5
// 5562.955 us; speedup vs baseline: 2.6261x; 2.6261x over previous
//
#include <hip/hip_runtime.h>
#include <math.h>

typedef _Float16 f16;
typedef f16 f16x2 __attribute__((ext_vector_type(2)));
typedef f16 f16x4 __attribute__((ext_vector_type(4)));
typedef f16 f16x8 __attribute__((ext_vector_type(8)));
typedef float f32x4 __attribute__((ext_vector_type(4)));

#define HDIM 1024
#define SEQ  2048
#define NBLK 16
#define RPB  64   // rows of W_hh per block

// ---------------- clear pairs + summary tags ----------------
// pairs row 0 cleared to (tag=0,payload=0) doubles as h_0 = 0; summ row 0
// cleared to 0 == tag for row 0, so step 1's gate passes immediately.
__global__ void k_clear(unsigned long long* __restrict__ p, int n,
                        unsigned* __restrict__ summ, int ns) {
  int stride = gridDim.x * blockDim.x;
  for (int i = blockIdx.x * blockDim.x + threadIdx.x; i < n; i += stride)
    p[i] = 0ULL;
  for (int i = blockIdx.x * blockDim.x + threadIdx.x; i < ns; i += stride)
    summ[i] = 0u;
}

// ---------------- f32 -> f16 convert (vec4, grid-stride) ----------------
__global__ void k_cvt(const float* __restrict__ in, f16* __restrict__ out, int n4) {
  int stride = gridDim.x * blockDim.x;
  for (int i = blockIdx.x * blockDim.x + threadIdx.x; i < n4; i += stride) {
    float4 v = ((const float4*)in)[i];
    f16x4 o = { (f16)v.x, (f16)v.y, (f16)v.z, (f16)v.w };
    ((f16x4*)out)[i] = o;
  }
}

__global__ void k_bias(const float* __restrict__ a, const float* __restrict__ b,
                       float* __restrict__ o) {
  int i = blockIdx.x * blockDim.x + threadIdx.x;
  if (i < HDIM) o[i] = a[i] + b[i];
}

// ---------------- B^T GEMM:  C[M][N] = A[M][K=1024] * B[N][K=1024]^T + bias[N]
__global__ __launch_bounds__(256) void k_gemm(
    const f16* __restrict__ A, const f16* __restrict__ B,
    const float* __restrict__ bias, float* __restrict__ C, int N)
{
  const int K = 1024;
  __shared__ __align__(16) f16 lsA[128 * 32];
  __shared__ __align__(16) f16 lsB[128 * 32];
  const int tid = threadIdx.x;
  const int l   = tid & 63;
  const int wv  = tid >> 6;
  const int mb  = blockIdx.y * 128;
  const int nb  = blockIdx.x * 128;
  const int wm  = (wv >> 1) * 64;
  const int wn  = (wv & 1) * 64;

  f32x4 acc[4][4] = {};

  for (int kt = 0; kt < K; kt += 32) {
    uint4 ra[2], rb[2];
#pragma unroll
    for (int i = 0; i < 2; ++i) {
      int c = tid + i * 256;
      int row = c >> 2, off = (c & 3) * 8;
      ra[i] = *(const uint4*)(A + (size_t)(mb + row) * K + kt + off);
      rb[i] = *(const uint4*)(B + (size_t)(nb + row) * K + kt + off);
    }
    __syncthreads();
#pragma unroll
    for (int i = 0; i < 2; ++i) {
      int c = tid + i * 256;
      *(uint4*)(lsA + c * 8) = ra[i];
      *(uint4*)(lsB + c * 8) = rb[i];
    }
    __syncthreads();

    f16x8 af[4], bf[4];
#pragma unroll
    for (int m = 0; m < 4; ++m)
      af[m] = *(const f16x8*)(lsA + (wm + m * 16 + (l & 15)) * 32 + (l >> 4) * 8);
#pragma unroll
    for (int n = 0; n < 4; ++n)
      bf[n] = *(const f16x8*)(lsB + (wn + n * 16 + (l & 15)) * 32 + (l >> 4) * 8);
#pragma unroll
    for (int m = 0; m < 4; ++m)
#pragma unroll
      for (int n = 0; n < 4; ++n)
        acc[m][n] = __builtin_amdgcn_mfma_f32_16x16x32_f16(af[m], bf[n], acc[m][n], 0, 0, 0);
  }

#pragma unroll
  for (int n = 0; n < 4; ++n) {
    int col = nb + wn + n * 16 + (l & 15);
    float bv = bias[col];
#pragma unroll
    for (int m = 0; m < 4; ++m) {
#pragma unroll
      for (int j = 0; j < 4; ++j) {
        int row = mb + wm + m * 16 + (l >> 4) * 4 + j;
        C[(size_t)row * N + col] = acc[m][n][j] + bv;
      }
    }
  }
}

// ---------------- sequential recurrence: 16 persistent blocks ----------------
// R3 comm primitives (relaxed agent-scope atomics; tag-in-data payloads) plus
// a SUMMARY-TAG GATE to kill poll contention: per step each block publishes
// one u32 (all 16 tags share one 64B line). Wave-0 lanes 0-15 spin on that
// single line (1 coalesced request per block per sweep, ~60x less poll
// traffic than sweeping 512 payload words). After the gate, one validated
// payload sweep; embedded tags absorb any store-completion reorder, so no
// fences anywhere. Barrier-B puts all payload stores before the summary
// store in issue order, making validation retries rare.
__global__ __launch_bounds__(1024) void k_recur(
    const float* __restrict__ W,              // W_hh f32 [H][H]
    const float* __restrict__ xp,             // [SEQ][H] f32
    unsigned long long* __restrict__ pairs,   // [(SEQ+1)*512] tag<<32|f16x2
    unsigned* __restrict__ summ,              // [(SEQ+1)*16] block tags
    f16* __restrict__ hs)                     // [(SEQ+1)][H] clean copy
{
  __shared__ unsigned hl[544];     // 17-stride swizzle
  __shared__ int s_dead;

  const int b   = blockIdx.x;
  const int tid = threadIdx.x;
  const int w   = tid >> 6;
  const int l   = tid & 63;
  const int hfl = l >> 5;
  const int ch  = l & 31;
  const int r0  = b * RPB + w * 4 + hfl * 2;
  const int c0  = ch * 32;

  if (tid == 0) s_dead = 0;

  // load + convert this thread's 2x32 weight slice into packed half2 regs
  f16x2 wv0[16], wv1[16];
  {
    const float* w0 = W + (size_t)r0 * HDIM + c0;
    const float* w1 = w0 + HDIM;
#pragma unroll
    for (int j = 0; j < 16; ++j) {
      wv0[j] = f16x2{ (f16)w0[2 * j], (f16)w0[2 * j + 1] };
      wv1[j] = f16x2{ (f16)w1[2 * j], (f16)w1[2 * j + 1] };
    }
  }

  for (unsigned t = 1; t <= SEQ; ++t) {
    // prefetch xp early (independent -> hides under gate)
    float x0 = 0.f, x1 = 0.f;
    if (ch == 0) {
      const float* xr = xp + (size_t)(t - 1) * HDIM + r0;
      x0 = xr[0]; x1 = xr[1];
    }

    if (w == 0) {
      const unsigned need = t - 1;
      // ---- gate: lanes 0-15 poll the 16-tag line of row t-1 ----
      {
        const unsigned* sp = summ + (size_t)(t - 1) * 16 + l;
        int g = 0;
        for (;;) {
          unsigned sv = need;
          if (l < 16)
            sv = __hip_atomic_load(sp, __ATOMIC_RELAXED, __HIP_MEMORY_SCOPE_AGENT);
          if (__ballot(sv != need) == 0ULL) break;
          if (++g > (1 << 20)) { if (l == 0) s_dead = 1; break; }
        }
      }
      // ---- one validated payload sweep (retries rare) ----
      const unsigned long long* row = pairs + (size_t)(t - 1) * 512 + l * 8;
      unsigned long long u[8];
      {
        int g = 0;
        for (;;) {
          bool ok = true;
#pragma unroll
          for (int j = 0; j < 8; ++j)
            u[j] = __hip_atomic_load(row + j, __ATOMIC_RELAXED,
                                     __HIP_MEMORY_SCOPE_AGENT);
#pragma unroll
          for (int j = 0; j < 8; ++j)
            ok &= ((unsigned)(u[j] >> 32) == (t - 1));
          if (__ballot(!ok) == 0ULL) break;
          if (++g > (1 << 20)) { if (l == 0) s_dead = 1; break; }
        }
      }
      const int base = (l >> 1) * 17 + (l & 1) * 8;
#pragma unroll
      for (int j = 0; j < 8; ++j) hl[base + j] = (unsigned)u[j];
    }
    __syncthreads();                 // barrier A: hl ready
    if (s_dead) return;              // abort cleanly together (fail-fast)

    float s0 = 0.f, s1 = 0.f;
#pragma unroll
    for (int j = 0; j < 16; ++j) {
      f16x2 hv = __builtin_bit_cast(f16x2, hl[ch * 17 + j]);
      s0 = __builtin_amdgcn_fdot2(wv0[j], hv, s0, false);
      s1 = __builtin_amdgcn_fdot2(wv1[j], hv, s1, false);
    }
#pragma unroll
    for (int m = 16; m >= 1; m >>= 1) {
      s0 += __shfl_xor(s0, m, 64);
      s1 += __shfl_xor(s1, m, 64);
    }

    if (ch == 0) {
      // fast tanh: 1 - 2/(e^{2x}+1); |err| ~1e-6 << f16 storage rounding
      float a0 = x0 + s0, a1 = x1 + s1;
      float e0 = __expf(2.f * a0), e1 = __expf(2.f * a1);
      float h0 = 1.f - 2.f * __builtin_amdgcn_rcpf(e0 + 1.f);
      float h1 = 1.f - 2.f * __builtin_amdgcn_rcpf(e1 + 1.f);
      f16x2 hh = { (f16)h0, (f16)h1 };
      unsigned pay = __builtin_bit_cast(unsigned, hh);
      unsigned long long val = ((unsigned long long)t << 32) | (unsigned long long)pay;
      __hip_atomic_store(pairs + (size_t)t * 512 + (r0 >> 1), val,
                         __ATOMIC_RELAXED, __HIP_MEMORY_SCOPE_AGENT);
      *(f16x2*)(hs + (size_t)t * HDIM + r0) = hh;   // clean copy for head GEMM
    }

    __syncthreads();                 // barrier B: payload stores issued first
    if (tid == 0)
      __hip_atomic_store(summ + (size_t)t * 16 + b, t,
                         __ATOMIC_RELAXED, __HIP_MEMORY_SCOPE_AGENT);
  }
}

// ---------------- launch ----------------
extern "C" void kernel_launch(void* const* d_in, const int* in_sizes, int n_in,
                              void* d_out, int out_size, void* d_ws, size_t ws_size,
                              hipStream_t stream) {
  const float* x    = (const float*)d_in[0];
  const float* W_ih = (const float*)d_in[1];
  const float* W_hh = (const float*)d_in[2];
  const float* b_ih = (const float*)d_in[3];
  const float* b_hh = (const float*)d_in[4];
  const float* W_fc = (const float*)d_in[5];
  const float* b_fc = (const float*)d_in[6];
  float* out = (float*)d_out;                  // [2048][32000] f32 = 262,144,000 B

  char* ws = (char*)d_ws;
  unsigned long long* pairs = (unsigned long long*)ws;       // 8,392,704 B
  f16*   hs16  = (f16*)(ws + 8500000);                       // 4,196,352
  float* xp    = (float*)(ws + 12700000);                    // 8,388,608
  f16*   x16   = (f16*)(ws + 21100000);                      // 4,194,304
  f16*   wih16 = (f16*)(ws + 25300000);                      // 2,097,152
  f16*   wfc16 = (f16*)(ws + 27400000);                      // 65,536,000
  float* bsum  = (float*)(ws + 92936000);                    // 4,096

  // summary tags live in the TAIL of d_out: dead storage until the head GEMM
  // (which runs strictly after k_recur) overwrites it. (SEQ+1)*16*4 = 131,136 B.
  unsigned* summ = (unsigned*)((char*)d_out + 262144000 - 131136);

  k_clear<<<1024, 256, 0, stream>>>(pairs, (SEQ + 1) * 512, summ, (SEQ + 1) * 16);
  k_cvt<<<1024, 256, 0, stream>>>(x, x16, 2048 * 1024 / 4);
  k_cvt<<<1024, 256, 0, stream>>>(W_ih, wih16, 1024 * 1024 / 4);
  k_cvt<<<2048, 256, 0, stream>>>(W_fc, wfc16, 32000 * 1024 / 4);
  k_bias<<<4, 256, 0, stream>>>(b_ih, b_hh, bsum);

  k_gemm<<<dim3(8, 16), 256, 0, stream>>>(x16, wih16, bsum, xp, 1024);

  k_recur<<<NBLK, 1024, 0, stream>>>(W_hh, xp, pairs, summ, hs16);

  k_gemm<<<dim3(250, 16), 256, 0, stream>>>(hs16 + HDIM, wfc16, b_fc, out, 32000);
}